// Round 1
// baseline (378.145 us; speedup 1.0000x reference)
//
#include <hip/hip_runtime.h>
#include <hip/hip_bf16.h>
#include <stdint.h>

// Causal self-attention, B=4, N=2048, D=1024 (single head, full-D scores).
// Pipeline: f32->bf16 converts; QKV GEMMs (bf16 MFMA, bias fused); V transpose;
// S = Q@K^T * 1/32 (causal tile skip, fp32 out); row softmax -> P bf16 (zeros
// above diagonal); ctx = P@Vt^T (k-limited); out = ctx@Wo^T + bo (fp32).
// Workspace requirement: 200 MiB.

typedef __hip_bfloat16 bf16;
typedef short bf16x8v __attribute__((ext_vector_type(8)));
typedef short bf16x4v __attribute__((ext_vector_type(4)));
typedef float f32x4   __attribute__((ext_vector_type(4)));

#define DEV static __device__ __forceinline__

DEV void gload_lds16(const void* g, void* l) {
  __builtin_amdgcn_global_load_lds(
      (const __attribute__((address_space(1))) void*)g,
      (__attribute__((address_space(3))) void*)l, 16u, 0, 0u);
}

struct alignas(8) bf16q { bf16 a, b, c, d; };

// ---------------- f32 -> bf16 convert, 4 elems/thread ----------------
__global__ __launch_bounds__(256)
void k_f32_to_bf16(const float* __restrict__ in, bf16* __restrict__ out, long n4) {
  long i = (long)blockIdx.x * blockDim.x + threadIdx.x;
  if (i >= n4) return;
  float4 v = ((const float4*)in)[i];
  bf16q o{__float2bfloat16(v.x), __float2bfloat16(v.y),
          __float2bfloat16(v.z), __float2bfloat16(v.w)};
  ((bf16q*)out)[i] = o;
}

// ---------------- MFMA GEMM: C = A(MxK) @ B(NxK)^T [+bias] ----------------
// 128x128 tile, BK=32, 4 waves (2x2), each wave 64x64 = 4x4 frags of 16x16x32.
// CAUSAL: 0 = none, 1 = skip tiles above diagonal (S), 2 = limit k (PV).
template<bool OUT_BF16, bool HAS_BIAS, int CAUSAL>
__global__ __launch_bounds__(256)
void k_gemm_bt(const bf16* __restrict__ A, const bf16* __restrict__ B,
               const float* __restrict__ bias, void* __restrict__ Cout,
               int M, int N, int K, float scale,
               long sA, long sB, long sC)
{
  const int tn = blockIdx.x, tm = blockIdx.y, bz = blockIdx.z;
  if (CAUSAL == 1 && tn > tm) return;  // fully-masked tile
  const bf16* Ab = A + (long)bz * sA;
  const bf16* Bb = B + (long)bz * sB;

  __shared__ bf16 As[128 * 32];
  __shared__ bf16 Bs[128 * 32];

  const int t = threadIdx.x;
  const int lane = t & 63;
  const int w = t >> 6;
  const int wr = w >> 1, wc = w & 1;

  f32x4 acc[4][4] = {};

  const int m0 = tm * 128, n0 = tn * 128;
  const int srow = t >> 2;          // staging row 0..63 (+64 second round)
  const int scol = (t & 3) * 8;     // staging col {0,8,16,24}

  int kend = K;
  if (CAUSAL == 2) { int ke = (tm + 1) * 128; kend = ke < K ? ke : K; }

  const int fr = lane & 15;
  const int kc = (lane >> 4) * 8;

  for (int k0 = 0; k0 < kend; k0 += 32) {
#pragma unroll
    for (int r = 0; r < 2; ++r) {
      int row = srow + r * 64;
      gload_lds16(Ab + (long)(m0 + row) * K + (k0 + scol), &As[row * 32 + scol]);
      gload_lds16(Bb + (long)(n0 + row) * K + (k0 + scol), &Bs[row * 32 + scol]);
    }
    __syncthreads();

    bf16x8v af[4], bf_[4];
#pragma unroll
    for (int i = 0; i < 4; i++)
      af[i] = *(const bf16x8v*)&As[(wr * 64 + i * 16 + fr) * 32 + kc];
#pragma unroll
    for (int j = 0; j < 4; j++)
      bf_[j] = *(const bf16x8v*)&Bs[(wc * 64 + j * 16 + fr) * 32 + kc];

#pragma unroll
    for (int i = 0; i < 4; i++)
#pragma unroll
      for (int j = 0; j < 4; j++)
        acc[i][j] = __builtin_amdgcn_mfma_f32_16x16x32_bf16(af[i], bf_[j], acc[i][j], 0, 0, 0);

    __syncthreads();
  }

  // Epilogue: C/D layout col = lane&15, row = (lane>>4)*4 + reg  [m89/m91]
  const int rq = (lane >> 4) * 4;
#pragma unroll
  for (int i = 0; i < 4; i++) {
#pragma unroll
    for (int j = 0; j < 4; j++) {
#pragma unroll
      for (int r = 0; r < 4; r++) {
        int m = m0 + wr * 64 + i * 16 + rq + r;
        int n = n0 + wc * 64 + j * 16 + fr;
        float v = acc[i][j][r] * scale;
        if (HAS_BIAS) v += bias[n];
        if (OUT_BF16)
          ((bf16*)Cout + (long)bz * sC)[(long)m * N + n] = __float2bfloat16(v);
        else
          ((float*)Cout + (long)bz * sC)[(long)m * N + n] = v;
      }
    }
  }
}

// ---------------- causal row softmax: S fp32 -> P bf16 ----------------
// one block (256 thr) per row; P[k>q] = 0 exactly.
__global__ __launch_bounds__(256)
void k_softmax_causal(const float* __restrict__ S, bf16* __restrict__ P) {
  const long row = blockIdx.x;
  const int q = (int)(row & 2047);
  const float* s = S + row * 2048;
  bf16* p = P + row * 2048;
  const int t = threadIdx.x;

  float e[8];
  float m = -3.4e38f;
#pragma unroll
  for (int i = 0; i < 8; i++) {
    int k = t + i * 256;
    float v = (k <= q) ? s[k] : -3.4e38f;
    e[i] = v;
    m = fmaxf(m, v);
  }
#pragma unroll
  for (int off = 1; off < 64; off <<= 1) m = fmaxf(m, __shfl_xor(m, off, 64));
  __shared__ float red[8];
  if ((t & 63) == 0) red[t >> 6] = m;
  __syncthreads();
  m = fmaxf(fmaxf(red[0], red[1]), fmaxf(red[2], red[3]));

  float sum = 0.f;
#pragma unroll
  for (int i = 0; i < 8; i++) {
    int k = t + i * 256;
    float x = (k <= q) ? __expf(e[i] - m) : 0.f;
    e[i] = x;
    sum += x;
  }
#pragma unroll
  for (int off = 1; off < 64; off <<= 1) sum += __shfl_xor(sum, off, 64);
  if ((t & 63) == 0) red[4 + (t >> 6)] = sum;
  __syncthreads();
  sum = red[4] + red[5] + red[6] + red[7];
  float inv = 1.f / sum;
#pragma unroll
  for (int i = 0; i < 8; i++) {
    int k = t + i * 256;
    p[k] = __float2bfloat16(e[i] * inv);
  }
}

// ---------------- bf16 transpose: Vt[d][k] = V[k][d], per batch z ----------------
__global__ __launch_bounds__(256)
void k_transpose_bf16(const bf16* __restrict__ V, bf16* __restrict__ Vt,
                      int rows, int cols) {
  __shared__ bf16 tile[64][68];
  const long bo = (long)blockIdx.z * (long)rows * cols;
  const bf16* v = V + bo;
  bf16* vt = Vt + bo;
  const int k0 = blockIdx.y * 64;
  const int d0 = blockIdx.x * 64;
  const int t = threadIdx.x;
  const int c4 = (t & 15) * 4;
  const int r = t >> 4;  // 0..15
#pragma unroll
  for (int p2 = 0; p2 < 4; p2++) {
    int row = r + p2 * 16;
    bf16x4v val = *(const bf16x4v*)&v[(long)(k0 + row) * cols + d0 + c4];
    *(bf16x4v*)&tile[row][c4] = val;
  }
  __syncthreads();
#pragma unroll
  for (int p2 = 0; p2 < 4; p2++) {
    int drow = r + p2 * 16;
    bf16q o{tile[c4 + 0][drow], tile[c4 + 1][drow],
            tile[c4 + 2][drow], tile[c4 + 3][drow]};
    *(bf16q*)&vt[(long)(d0 + drow) * rows + k0 + c4] = o;
  }
}

// ---------------- launch ----------------
extern "C" void kernel_launch(void* const* d_in, const int* in_sizes, int n_in,
                              void* d_out, int out_size, void* d_ws, size_t ws_size,
                              hipStream_t stream)
{
  const float* X  = (const float*)d_in[0];
  const float* Wq = (const float*)d_in[1];
  const float* bq = (const float*)d_in[2];
  const float* Wk = (const float*)d_in[3];
  const float* bk = (const float*)d_in[4];
  const float* Wv = (const float*)d_in[5];
  const float* bv = (const float*)d_in[6];
  const float* Wo = (const float*)d_in[7];
  const float* bo = (const float*)d_in[8];

  const long Nt = 2048, D = 1024;
  const long TOK = 4 * Nt;  // 8192

  char* ws = (char*)d_ws;
  const size_t MB = 1024 * 1024;
  bf16* Xb  = (bf16*)(ws + 0);        // 16 MiB
  bf16* Wqb = (bf16*)(ws + 16 * MB);  //  2 MiB
  bf16* Wkb = (bf16*)(ws + 18 * MB);
  bf16* Wvb = (bf16*)(ws + 20 * MB);
  bf16* Wob = (bf16*)(ws + 22 * MB);
  bf16* Qb  = (bf16*)(ws + 24 * MB);  // 16 MiB
  bf16* Kb  = (bf16*)(ws + 40 * MB);
  bf16* Vb  = (bf16*)(ws + 56 * MB);
  bf16* Vt  = (bf16*)(ws + 72 * MB);
  bf16* Cx  = (bf16*)(ws + 88 * MB);  // 16 MiB
  float* Sf = (float*)(ws + 104 * MB); // 64 MiB
  bf16* Pb  = (bf16*)(ws + 168 * MB);  // 32 MiB -> total 200 MiB

  dim3 blk(256);

  // converts
  k_f32_to_bf16<<<dim3(8192), blk, 0, stream>>>(X,  Xb,  TOK * D / 4);
  k_f32_to_bf16<<<dim3(1024), blk, 0, stream>>>(Wq, Wqb, D * D / 4);
  k_f32_to_bf16<<<dim3(1024), blk, 0, stream>>>(Wk, Wkb, D * D / 4);
  k_f32_to_bf16<<<dim3(1024), blk, 0, stream>>>(Wv, Wvb, D * D / 4);
  k_f32_to_bf16<<<dim3(1024), blk, 0, stream>>>(Wo, Wob, D * D / 4);

  // QKV projections: [8192,1024] = Xb @ W^T + b
  k_gemm_bt<true, true, 0><<<dim3(8, 64, 1), blk, 0, stream>>>(
      Xb, Wqb, bq, Qb, 8192, 1024, 1024, 1.f, 0, 0, 0);
  k_gemm_bt<true, true, 0><<<dim3(8, 64, 1), blk, 0, stream>>>(
      Xb, Wkb, bk, Kb, 8192, 1024, 1024, 1.f, 0, 0, 0);
  k_gemm_bt<true, true, 0><<<dim3(8, 64, 1), blk, 0, stream>>>(
      Xb, Wvb, bv, Vb, 8192, 1024, 1024, 1.f, 0, 0, 0);

  // V transpose per batch: Vt[b][d][k]
  k_transpose_bf16<<<dim3(16, 32, 4), blk, 0, stream>>>(Vb, Vt, 2048, 1024);

  // S = Q @ K^T / 32, causal tile skip, fp32
  k_gemm_bt<false, false, 1><<<dim3(16, 16, 4), blk, 0, stream>>>(
      Qb, Kb, nullptr, Sf, 2048, 2048, 1024, 0.03125f,
      Nt * D, Nt * D, Nt * Nt);

  // row softmax -> P bf16
  k_softmax_causal<<<dim3(8192), blk, 0, stream>>>(Sf, Pb);

  // ctx = P @ Vt^T (k limited per q-tile)
  k_gemm_bt<true, false, 2><<<dim3(8, 16, 4), blk, 0, stream>>>(
      Pb, Vt, nullptr, Cx, 2048, 1024, 2048, 1.f,
      Nt * Nt, D * Nt, Nt * D);

  // out = ctx @ Wo^T + bo (fp32)
  k_gemm_bt<false, true, 0><<<dim3(8, 64, 1), blk, 0, stream>>>(
      Cx, Wob, bo, d_out, 8192, 1024, 1024, 1.f, 0, 0, 0);
}

// Round 2
// 332.250 us; speedup vs baseline: 1.1381x; 1.1381x over previous
//
#include <hip/hip_runtime.h>
#include <hip/hip_bf16.h>
#include <stdint.h>

// Causal self-attention, B=4, N=2048, D=1024 (single head, full-D scores).
// R2: fused QKV GEMM (N=3072), 2-phase double-buffered K-loop in all GEMMs,
// causal-trimmed softmax.

typedef __hip_bfloat16 bf16;
typedef short bf16x8v __attribute__((ext_vector_type(8)));
typedef short bf16x4v __attribute__((ext_vector_type(4)));
typedef float f32x4   __attribute__((ext_vector_type(4)));

#define DEV static __device__ __forceinline__

DEV void gload_lds16(const void* g, void* l) {
  __builtin_amdgcn_global_load_lds(
      (const __attribute__((address_space(1))) void*)g,
      (__attribute__((address_space(3))) void*)l, 16u, 0, 0u);
}

struct alignas(8) bf16q { bf16 a, b, c, d; };

// ---------------- f32 -> bf16 convert, 4 elems/thread ----------------
__global__ __launch_bounds__(256)
void k_f32_to_bf16(const float* __restrict__ in, bf16* __restrict__ out, long n4) {
  long i = (long)blockIdx.x * blockDim.x + threadIdx.x;
  if (i >= n4) return;
  float4 v = ((const float4*)in)[i];
  bf16q o{__float2bfloat16(v.x), __float2bfloat16(v.y),
          __float2bfloat16(v.z), __float2bfloat16(v.w)};
  ((bf16q*)out)[i] = o;
}

// ---------------- MFMA GEMM: C = A(MxK) @ B(NxK)^T [+bias] ----------------
// 128x128 tile, BK=32, 4 waves (2x2), each wave 64x64 = 4x4 frags of 16x16x32.
// 2-phase double-buffered: STAGE(t+1) issued before compute(t); 1 barrier/K-step.
// CAUSAL: 0 = none, 1 = skip tiles above diagonal (S), 2 = limit k (PV).
template<bool OUT_BF16, bool HAS_BIAS, int CAUSAL>
__global__ __launch_bounds__(256)
void k_gemm_bt(const bf16* __restrict__ A, const bf16* __restrict__ B,
               const float* __restrict__ bias, void* __restrict__ Cout,
               int M, int N, int K, float scale,
               int lda, int ldb, int ldc,
               long sA, long sB, long sC)
{
  const int tn = blockIdx.x, tm = blockIdx.y, bz = blockIdx.z;
  if (CAUSAL == 1 && tn > tm) return;  // fully-masked tile
  const bf16* Ab = A + (long)bz * sA;
  const bf16* Bb = B + (long)bz * sB;

  __shared__ bf16 As[2][128 * 32];
  __shared__ bf16 Bs[2][128 * 32];

  const int t = threadIdx.x;
  const int lane = t & 63;
  const int w = t >> 6;
  const int wr = w >> 1, wc = w & 1;

  f32x4 acc[4][4] = {};

  const int m0 = tm * 128, n0 = tn * 128;
  const int srow = t >> 2;          // staging row 0..63 (+64 second round)
  const int scol = (t & 3) * 8;     // staging col {0,8,16,24}

  int kend = K;
  if (CAUSAL == 2) { int ke = (tm + 1) * 128; kend = ke < K ? ke : K; }
  const int nt = kend >> 5;

  const int fr = lane & 15;
  const int kc = (lane >> 4) * 8;

  // prologue stage into buf 0
#pragma unroll
  for (int r = 0; r < 2; ++r) {
    int row = srow + r * 64;
    gload_lds16(Ab + (long)(m0 + row) * lda + scol, &As[0][row * 32 + scol]);
    gload_lds16(Bb + (long)(n0 + row) * ldb + scol, &Bs[0][row * 32 + scol]);
  }
  __syncthreads();

  int cur = 0;
  for (int ts = 0; ts < nt; ++ts) {
    if (ts + 1 < nt) {
      int k0 = (ts + 1) << 5;
#pragma unroll
      for (int r = 0; r < 2; ++r) {
        int row = srow + r * 64;
        gload_lds16(Ab + (long)(m0 + row) * lda + (k0 + scol), &As[cur ^ 1][row * 32 + scol]);
        gload_lds16(Bb + (long)(n0 + row) * ldb + (k0 + scol), &Bs[cur ^ 1][row * 32 + scol]);
      }
    }

    bf16x8v af[4], bf_[4];
#pragma unroll
    for (int i = 0; i < 4; i++)
      af[i] = *(const bf16x8v*)&As[cur][(wr * 64 + i * 16 + fr) * 32 + kc];
#pragma unroll
    for (int j = 0; j < 4; j++)
      bf_[j] = *(const bf16x8v*)&Bs[cur][(wc * 64 + j * 16 + fr) * 32 + kc];

#pragma unroll
    for (int i = 0; i < 4; i++)
#pragma unroll
      for (int j = 0; j < 4; j++)
        acc[i][j] = __builtin_amdgcn_mfma_f32_16x16x32_bf16(af[i], bf_[j], acc[i][j], 0, 0, 0);

    __syncthreads();  // drains vmcnt (next-tile stage) + lgkm; all reads done
    cur ^= 1;
  }

  // Epilogue: C/D layout col = lane&15, row = (lane>>4)*4 + reg  [m89/m91]
  const int rq = (lane >> 4) * 4;
#pragma unroll
  for (int i = 0; i < 4; i++) {
#pragma unroll
    for (int j = 0; j < 4; j++) {
#pragma unroll
      for (int r = 0; r < 4; r++) {
        int m = m0 + wr * 64 + i * 16 + rq + r;
        int n = n0 + wc * 64 + j * 16 + fr;
        float v = acc[i][j][r] * scale;
        if (HAS_BIAS) v += bias[n];
        if (OUT_BF16)
          ((bf16*)Cout + (long)bz * sC)[(long)m * ldc + n] = __float2bfloat16(v);
        else
          ((float*)Cout + (long)bz * sC)[(long)m * ldc + n] = v;
      }
    }
  }
}

// ---------------- causal row softmax: S fp32 -> P bf16 (trimmed) ----------------
// one block (256 thr) per row; writes P[k] for k < kend(q) only; P[k>q]=0.
__global__ __launch_bounds__(256)
void k_softmax_causal(const float* __restrict__ S, bf16* __restrict__ P) {
  const long row = blockIdx.x;
  const int q = (int)(row & 2047);
  const int kend = ((q >> 7) + 1) << 7;  // multiple of 128
  const float* s = S + row * 2048;
  bf16* p = P + row * 2048;
  const int t = threadIdx.x;

  float e[8];
  float m = -3.4e38f;
#pragma unroll
  for (int i = 0; i < 8; i++) {
    int k = t + i * 256;
    float v = -3.4e38f;
    if (k <= q) v = s[k];
    e[i] = v;
    m = fmaxf(m, v);
  }
#pragma unroll
  for (int off = 1; off < 64; off <<= 1) m = fmaxf(m, __shfl_xor(m, off, 64));
  __shared__ float red[8];
  if ((t & 63) == 0) red[t >> 6] = m;
  __syncthreads();
  m = fmaxf(fmaxf(red[0], red[1]), fmaxf(red[2], red[3]));

  float sum = 0.f;
#pragma unroll
  for (int i = 0; i < 8; i++) {
    int k = t + i * 256;
    float x = (k <= q) ? __expf(e[i] - m) : 0.f;
    e[i] = x;
    sum += x;
  }
#pragma unroll
  for (int off = 1; off < 64; off <<= 1) sum += __shfl_xor(sum, off, 64);
  if ((t & 63) == 0) red[4 + (t >> 6)] = sum;
  __syncthreads();
  sum = red[4] + red[5] + red[6] + red[7];
  float inv = 1.f / sum;
#pragma unroll
  for (int i = 0; i < 8; i++) {
    int k = t + i * 256;
    if (k < kend) p[k] = __float2bfloat16(e[i] * inv);
  }
}

// ---------------- bf16 transpose with strides: Vt[d][k] = V[k][d] ----------------
__global__ __launch_bounds__(256)
void k_transpose_bf16(const bf16* __restrict__ V, bf16* __restrict__ Vt,
                      int in_ld, int out_ld, long in_bs, long out_bs) {
  __shared__ bf16 tile[64][68];
  const bf16* v = V + (long)blockIdx.z * in_bs;
  bf16* vt = Vt + (long)blockIdx.z * out_bs;
  const int k0 = blockIdx.y * 64;
  const int d0 = blockIdx.x * 64;
  const int t = threadIdx.x;
  const int c4 = (t & 15) * 4;
  const int r = t >> 4;  // 0..15
#pragma unroll
  for (int p2 = 0; p2 < 4; p2++) {
    int row = r + p2 * 16;
    bf16x4v val = *(const bf16x4v*)&v[(long)(k0 + row) * in_ld + d0 + c4];
    *(bf16x4v*)&tile[row][c4] = val;
  }
  __syncthreads();
#pragma unroll
  for (int p2 = 0; p2 < 4; p2++) {
    int drow = r + p2 * 16;
    bf16q o{tile[c4 + 0][drow], tile[c4 + 1][drow],
            tile[c4 + 2][drow], tile[c4 + 3][drow]};
    *(bf16q*)&vt[(long)(d0 + drow) * out_ld + k0 + c4] = o;
  }
}

// ---------------- launch ----------------
extern "C" void kernel_launch(void* const* d_in, const int* in_sizes, int n_in,
                              void* d_out, int out_size, void* d_ws, size_t ws_size,
                              hipStream_t stream)
{
  const float* X  = (const float*)d_in[0];
  const float* Wq = (const float*)d_in[1];
  const float* bq = (const float*)d_in[2];
  const float* Wk = (const float*)d_in[3];
  const float* bk = (const float*)d_in[4];
  const float* Wv = (const float*)d_in[5];
  const float* bv = (const float*)d_in[6];
  const float* Wo = (const float*)d_in[7];
  const float* bo = (const float*)d_in[8];

  const long Nt = 2048, D = 1024;
  const long TOK = 4 * Nt;  // 8192

  char* ws = (char*)d_ws;
  const size_t MB = 1024 * 1024;
  // layout (MB offsets). Sf overlaps Xb (Xb dead after QKV GEMM).
  bf16*  QKVb = (bf16*)(ws + 0);          // 48 MiB  [8192][3072]
  bf16*  Wcat = (bf16*)(ws + 48 * MB);    //  6 MiB  [3072][1024]
  bf16*  Wob  = (bf16*)(ws + 54 * MB);    //  2 MiB
  float* bcat = (float*)(ws + 56 * MB);   //  12 KiB [3072]
  bf16*  Vt   = (bf16*)(ws + 57 * MB);    // 16 MiB  [4][1024][2048]
  bf16*  Cx   = (bf16*)(ws + 73 * MB);    // 16 MiB
  bf16*  Pb   = (bf16*)(ws + 89 * MB);    // 32 MiB
  bf16*  Xb   = (bf16*)(ws + 121 * MB);   // 16 MiB
  float* Sf   = (float*)(ws + 121 * MB);  // 64 MiB (overlaps Xb; ends 185)

  dim3 blk(256);

  // converts (weights concatenated into Wcat = [Wq; Wk; Wv])
  k_f32_to_bf16<<<dim3(8192), blk, 0, stream>>>(X,  Xb,  TOK * D / 4);
  k_f32_to_bf16<<<dim3(1024), blk, 0, stream>>>(Wq, Wcat,                Wq ? D * D / 4 : 0);
  k_f32_to_bf16<<<dim3(1024), blk, 0, stream>>>(Wk, Wcat + D * D,        D * D / 4);
  k_f32_to_bf16<<<dim3(1024), blk, 0, stream>>>(Wv, Wcat + 2 * D * D,    D * D / 4);
  k_f32_to_bf16<<<dim3(1024), blk, 0, stream>>>(Wo, Wob,                 D * D / 4);

  // bias concat [bq; bk; bv]
  hipMemcpyAsync(bcat,        bq, D * 4, hipMemcpyDeviceToDevice, stream);
  hipMemcpyAsync(bcat + D,    bk, D * 4, hipMemcpyDeviceToDevice, stream);
  hipMemcpyAsync(bcat + 2*D,  bv, D * 4, hipMemcpyDeviceToDevice, stream);

  // fused QKV projection: [8192,3072] = Xb @ Wcat^T + bcat
  k_gemm_bt<true, true, 0><<<dim3(24, 64, 1), blk, 0, stream>>>(
      Xb, Wcat, bcat, QKVb, 8192, 3072, 1024, 1.f,
      1024, 1024, 3072, 0, 0, 0);

  // V transpose per batch: Vt[b][d][k] (V = QKVb cols 2048..3071)
  k_transpose_bf16<<<dim3(16, 32, 4), blk, 0, stream>>>(
      QKVb + 2048, Vt, 3072, 2048, Nt * 3072, D * Nt);

  // S = Q @ K^T / 32, causal tile skip, fp32
  k_gemm_bt<false, false, 1><<<dim3(16, 16, 4), blk, 0, stream>>>(
      QKVb, QKVb + 1024, nullptr, Sf, 2048, 2048, 1024, 0.03125f,
      3072, 3072, 2048, Nt * 3072, Nt * 3072, Nt * Nt);

  // row softmax -> P bf16 (causal-trimmed)
  k_softmax_causal<<<dim3(8192), blk, 0, stream>>>(Sf, Pb);

  // ctx = P @ Vt^T (k limited per q-tile)
  k_gemm_bt<true, false, 2><<<dim3(8, 16, 4), blk, 0, stream>>>(
      Pb, Vt, nullptr, Cx, 2048, 1024, 2048, 1.f,
      2048, 2048, 1024, Nt * Nt, D * Nt, Nt * D);

  // out = ctx @ Wo^T + bo (fp32)
  k_gemm_bt<false, true, 0><<<dim3(8, 64, 1), blk, 0, stream>>>(
      Cx, Wob, bo, d_out, 8192, 1024, 1024, 1.f,
      1024, 1024, 1024, 0, 0, 0);
}